// Round 10
// baseline (4237.704 us; speedup 1.0000x reference)
//
#include <hip/hip_runtime.h>
#include <hip/hip_bf16.h>

// TrajectoryDecoder. L=3 GRU (H=512), T=64, B=2048. Round 10:
// R9 + ONE change: rebalanced GEMM bundles (3 phases <=512 blocks each).
//   B1 = gi1(192)+gh0'[0:64)        = 256 blocks
//   B2 = gi2(192)+gh1'[0:128)+gh0'[64:192) = 448 blocks
//   B3 = MLP(64)+gh2'(192)+gh1'[128:192)   = 320 blocks
// (gh'(t+1) tiles are off-critical-path; any later bundle of step t works.)
// Tile math unchanged -> bit-identical (absmax must stay 0.0625).
// Per step (6 launches): k_ew0 | k_tri B1 | k_ewl | k_tri B2 | k_ewl | k_tri B3

#define H 512
#define T_STEPS 64
#define BATCH 2048
#define H3 1536
#define D_IN 256
#define NSTRIP 8

typedef __bf16 bf16x8 __attribute__((ext_vector_type(8)));
typedef float f32x4 __attribute__((ext_vector_type(4)));
typedef unsigned short ushort8v __attribute__((ext_vector_type(8)));
typedef unsigned short ushort4v __attribute__((ext_vector_type(4)));

typedef const __attribute__((address_space(1))) unsigned int* gp1_t;
typedef __attribute__((address_space(3))) unsigned int* lp3_t;

__device__ inline void gload16(const unsigned short* g, unsigned short* l) {
    __builtin_amdgcn_global_load_lds((gp1_t)g, (lp3_t)l, 16, 0, 0);
}

__device__ inline unsigned short f2bf(float f) {
    union { float f; unsigned int u; } v{f};
    unsigned int r = v.u + 0x7fffu + ((v.u >> 16) & 1u);
    return (unsigned short)(r >> 16);
}
__device__ inline float bf2f(unsigned short u) {
    union { unsigned int u; float f; } v;
    v.u = ((unsigned int)u) << 16;
    return v.f;
}
__device__ inline float sigmoidf_(float x) { return 1.f / (1.f + expf(-x)); }

// LDS short-offset for fragment read at tile row r, k-chunk ko (XOR swizzle)
__device__ inline int soff(int r, int ko) {
    return r * 32 + ((ko ^ ((r >> 1) & 3)) << 3);
}

// stage 128 rows x 32 shorts (row stride ld) into linear LDS buf, swizzled src
__device__ inline void stage128(const unsigned short* src, int ld, int k0,
                                unsigned short* lds) {
    const int wid = threadIdx.x >> 6, lane = threadIdx.x & 63;
#pragma unroll
    for (int i = 0; i < 2; ++i) {
        int off = i * 4096 + wid * 1024 + lane * 16;  // byte offset in tile
        int row = off >> 6;
        int c = (off >> 4) & 3;
        int cs = c ^ ((row >> 1) & 3);
        gload16(src + (size_t)row * ld + k0 + cs * 8,
                lds + ((i * 4096 + wid * 1024) >> 1));
    }
}

// ---- 128x128 core, 2-phase double-buffered: acc = A @ W^T ----
__device__ inline void gcore(const unsigned short* A0, int lda,
                             const unsigned short* W0, int K,
                             unsigned short (*As)[4096], unsigned short (*Ws)[4096],
                             f32x4 (&acc)[4][4]) {
    const int lane = threadIdx.x & 63, wid = threadIdx.x >> 6;
    const int wr = wid >> 1, wc = wid & 1;
    const int r16 = lane & 15, ko = lane >> 4;
#pragma unroll
    for (int i = 0; i < 4; ++i)
#pragma unroll
        for (int j = 0; j < 4; ++j) acc[i][j] = (f32x4)0.f;
    int aoff[4], boff[4];
#pragma unroll
    for (int i = 0; i < 4; ++i) {
        aoff[i] = soff(wr * 64 + i * 16 + r16, ko);
        boff[i] = soff(wc * 64 + i * 16 + r16, ko);
    }
    stage128(A0, lda, 0, As[0]);
    stage128(W0, K, 0, Ws[0]);
    __syncthreads();  // drains vmcnt(0)
    int cur = 0;
    for (int k0 = 0; k0 < K; k0 += 32) {
        const bool more = (k0 + 32) < K;
        if (more) {  // prefetch next tile into other buffer (overlaps MFMA)
            stage128(A0, lda, k0 + 32, As[cur ^ 1]);
            stage128(W0, K, k0 + 32, Ws[cur ^ 1]);
        }
        bf16x8 a[4], b[4];
#pragma unroll
        for (int i = 0; i < 4; ++i) a[i] = *(const bf16x8*)&As[cur][aoff[i]];
#pragma unroll
        for (int i = 0; i < 4; ++i) b[i] = *(const bf16x8*)&Ws[cur][boff[i]];
#pragma unroll
        for (int mi = 0; mi < 4; ++mi)
#pragma unroll
            for (int ni = 0; ni < 4; ++ni)
                acc[mi][ni] = __builtin_amdgcn_mfma_f32_16x16x32_bf16(
                    a[mi], b[ni], acc[mi][ni], 0, 0, 0);
        if (more) {
            __syncthreads();  // next buffer written (vmcnt drain) + reads done
            cur ^= 1;
        }
    }
}

// fp32 (+ optional bf16 shadow) epilogue — used for h init
__device__ inline void epilogue_f32(f32x4 (&acc)[4][4], float* C, int ldc,
                                    const float* bias, unsigned short* Cbf,
                                    int brow, int bcol) {
    const int lane = threadIdx.x & 63, wid = threadIdx.x >> 6;
    const int wr = wid >> 1, wc = wid & 1, r16 = lane & 15;
    const int crow0 = brow + wr * 64 + (lane >> 4) * 4;
    const int ccol0 = bcol + wc * 64 + r16;
#pragma unroll
    for (int mi = 0; mi < 4; ++mi)
#pragma unroll
        for (int ni = 0; ni < 4; ++ni) {
            int col = ccol0 + ni * 16;
            float bv = bias ? bias[col] : 0.f;
#pragma unroll
            for (int j = 0; j < 4; ++j) {
                int row = crow0 + mi * 16 + j;
                float v = acc[mi][ni][j] + bv;
                C[(size_t)row * ldc + col] = v;
                if (Cbf) Cbf[(size_t)row * ldc + col] = f2bf(v);
            }
        }
}

// bf16 epilogue — used for gate buffers (gi, gh)
__device__ inline void epilogue_bf(f32x4 (&acc)[4][4], unsigned short* C, int ldc,
                                   int brow, int bcol) {
    const int lane = threadIdx.x & 63, wid = threadIdx.x >> 6;
    const int wr = wid >> 1, wc = wid & 1, r16 = lane & 15;
    const int crow0 = brow + wr * 64 + (lane >> 4) * 4;
    const int ccol0 = bcol + wc * 64 + r16;
#pragma unroll
    for (int mi = 0; mi < 4; ++mi)
#pragma unroll
        for (int ni = 0; ni < 4; ++ni) {
            int col = ccol0 + ni * 16;
#pragma unroll
            for (int j = 0; j < 4; ++j) {
                int row = crow0 + mi * 16 + j;
                C[(size_t)row * ldc + col] = f2bf(acc[mi][ni][j]);
            }
        }
}

// MLP epilogue: hid = relu(acc+b1); partials[strip][row][2] = hid @ W2-slice
__device__ inline void epilogue_mlp(f32x4 (&acc)[4][4], const float* b1t,
                                    const float* W2t, float* partials, int brow,
                                    int bcol) {
    const int lane = threadIdx.x & 63, wid = threadIdx.x >> 6;
    const int wr = wid >> 1, wc = wid & 1, r16 = lane & 15;
    const int crow0 = brow + wr * 64 + (lane >> 4) * 4;
    const int ccol0 = bcol + wc * 64 + r16;
    const int strip = (bcol >> 7) * 2 + wc;
    float d0[4][4], d1[4][4];
#pragma unroll
    for (int mi = 0; mi < 4; ++mi)
#pragma unroll
        for (int j = 0; j < 4; ++j) { d0[mi][j] = 0.f; d1[mi][j] = 0.f; }
#pragma unroll
    for (int ni = 0; ni < 4; ++ni) {
        int col = ccol0 + ni * 16;
        float bv = b1t[col];
        float w20 = W2t[col * 2 + 0], w21 = W2t[col * 2 + 1];
#pragma unroll
        for (int mi = 0; mi < 4; ++mi)
#pragma unroll
            for (int j = 0; j < 4; ++j) {
                float hv = fmaxf(acc[mi][ni][j] + bv, 0.f);
                d0[mi][j] += hv * w20;
                d1[mi][j] += hv * w21;
            }
    }
#pragma unroll
    for (int m = 1; m < 16; m <<= 1)
#pragma unroll
        for (int mi = 0; mi < 4; ++mi)
#pragma unroll
            for (int j = 0; j < 4; ++j) {
                d0[mi][j] += __shfl_xor(d0[mi][j], m);
                d1[mi][j] += __shfl_xor(d1[mi][j], m);
            }
    if (r16 == 0) {
#pragma unroll
        for (int mi = 0; mi < 4; ++mi)
#pragma unroll
            for (int j = 0; j < 4; ++j) {
                int row = crow0 + mi * 16 + j;
                float2 v = make_float2(d0[mi][j], d1[mi][j]);
                *(float2*)&partials[((size_t)strip * BATCH + row) * 2] = v;
            }
    }
}

// ---- tile-set descriptor ----
struct TD {
    const unsigned short* A;  // bf16 activations, row stride H3
    const unsigned short* W;  // bf16 weights, K-major (K=512)
    unsigned short* C;        // bf16 output, row stride H3
    int t0;                   // first tile index (within 16x12 tile grid)
};

// ---- bundled GEMM kernel: up to 3 tile sets; set0 may be the MLP ----
__global__ __launch_bounds__(256) void k_tri(TD d0, TD d1, TD d2, int n0, int n1,
                                             int mlp0, const float* b1t,
                                             const float* W2t, float* partials,
                                             int skipGh) {
    __shared__ unsigned short As[2][4096], Ws[2][4096];
    f32x4 acc[4][4];
    const int bid = blockIdx.x;
    TD d;
    int r, isMlp = 0;
    if (bid < n0) {
        d = d0; r = d0.t0 + bid; isMlp = mlp0;
    } else if (bid < n0 + n1) {
        if (skipGh) return;
        d = d1; r = d1.t0 + (bid - n0);
    } else {
        if (skipGh) return;
        d = d2; r = d2.t0 + (bid - n0 - n1);
    }
    if (isMlp) {
        int brow = (r >> 2) * 128, bcol = (r & 3) * 128;
        gcore(d.A + (size_t)brow * H3, H3, d.W + (size_t)bcol * H, H, As, Ws, acc);
        epilogue_mlp(acc, b1t, W2t, partials, brow, bcol);
    } else {
        int brow = (r / 12) * 128, bcol = (r % 12) * 128;
        gcore(d.A + (size_t)brow * H3, H3, d.W + (size_t)bcol * H, H, As, Ws, acc);
        epilogue_bf(acc, d.C, H3, brow, bcol);
    }
}

// ---- prologue GEMMs ----
__global__ __launch_bounds__(256) void k_init(const unsigned short* comb,
                                              const unsigned short* hpW, float* h,
                                              unsigned short* h_bf,
                                              const float* hp_b) {
    __shared__ unsigned short As[2][4096], Ws[2][4096];
    f32x4 acc[4][4];
    int bid = blockIdx.x;  // 192
    int brow = (bid / 12) * 128, bcol = (bid % 12) * 128;
    gcore(comb + (size_t)brow * D_IN, D_IN, hpW + (size_t)bcol * D_IN, D_IN, As, Ws,
          acc);
    epilogue_f32(acc, h, H3, hp_b, h_bf, brow, bcol);
}

__global__ __launch_bounds__(256) void k_gh3(const unsigned short* h_bf,
                                             const unsigned short* Whh,
                                             unsigned short* gh0, unsigned short* gh1,
                                             unsigned short* gh2) {
    __shared__ unsigned short As[2][4096], Ws[2][4096];
    f32x4 acc[4][4];
    int bid = blockIdx.x;  // 576
    int g = bid / 192, r = bid % 192;
    int brow = (r / 12) * 128, bcol = (r % 12) * 128;
    unsigned short* C = (g == 0) ? gh0 : (g == 1 ? gh1 : gh2);
    gcore(h_bf + g * H + (size_t)brow * H3, H3,
          Whh + (size_t)g * H3 * H + (size_t)bcol * H, H, As, Ws, acc);
    epilogue_bf(acc, C, H3, brow, bcol);
}

// ---- EW kernels (1024 blocks, 2 rows/block, 4 elems/thread) ----
__global__ __launch_bounds__(256) void k_ew0(const unsigned short* gh0, float* h,
                                             unsigned short* h_bf,
                                             const float* W_ih0, const float* b_ih,
                                             const float* b_hh, float* pos,
                                             const float* partials, const float* b2,
                                             float* out, int t) {
    __shared__ float posS[2][2];
    const int tid = threadIdx.x, bid = blockIdx.x;
    if (tid < 2) {
        int b = bid * 2 + tid;
        float p0 = pos[b * 2 + 0], p1 = pos[b * 2 + 1];
        if (t > 0) {
            float s0 = 0.f, s1 = 0.f;
#pragma unroll
            for (int s = 0; s < NSTRIP; ++s) {
                float2 v = *(const float2*)&partials[((size_t)s * BATCH + b) * 2];
                s0 += v.x; s1 += v.y;
            }
            p0 += s0 + b2[(t - 1) * 2 + 0];
            p1 += s1 + b2[(t - 1) * 2 + 1];
            pos[b * 2 + 0] = p0;
            pos[b * 2 + 1] = p1;
            out[((size_t)b * T_STEPS + (t - 1)) * 2 + 0] = p0;
            out[((size_t)b * T_STEPS + (t - 1)) * 2 + 1] = p1;
        }
        posS[tid][0] = p0;
        posS[tid][1] = p1;
    }
    __syncthreads();
    const int lrow = tid >> 7, j0 = (tid & 127) * 4;
    const int b = bid * 2 + lrow;
    const size_t rb = (size_t)b * H3;
    const float px = posS[lrow][0], py = posS[lrow][1];
    ushort4v g0 = *(const ushort4v*)&gh0[rb + j0];
    ushort4v g1 = *(const ushort4v*)&gh0[rb + 512 + j0];
    ushort4v g2 = *(const ushort4v*)&gh0[rb + 1024 + j0];
    float4 h4 = *(const float4*)&h[rb + j0];
    float hv[4] = {h4.x, h4.y, h4.z, h4.w};
    float4 ho;
    ushort4v hbo;
#pragma unroll
    for (int k = 0; k < 4; ++k) {
        int j = j0 + k;
        float gi_r = px * W_ih0[j * 2 + 0] + py * W_ih0[j * 2 + 1] + b_ih[j];
        float gi_z = px * W_ih0[(512 + j) * 2 + 0] + py * W_ih0[(512 + j) * 2 + 1] +
                     b_ih[512 + j];
        float gi_n = px * W_ih0[(1024 + j) * 2 + 0] + py * W_ih0[(1024 + j) * 2 + 1] +
                     b_ih[1024 + j];
        float r = sigmoidf_(gi_r + bf2f(g0[k]) + b_hh[j]);
        float zg = sigmoidf_(gi_z + bf2f(g1[k]) + b_hh[512 + j]);
        float n = tanhf(gi_n + r * (bf2f(g2[k]) + b_hh[1024 + j]));
        float nh = (1.f - zg) * n + zg * hv[k];
        ((float*)&ho)[k] = nh;
        hbo[k] = f2bf(nh);
    }
    *(float4*)&h[rb + j0] = ho;
    *(ushort4v*)&h_bf[rb + j0] = hbo;
}

__global__ __launch_bounds__(256) void k_ewl(const unsigned short* gi,
                                             const unsigned short* gh, float* h,
                                             unsigned short* h_bf,
                                             const float* b_ihl, const float* b_hhl,
                                             int colOff) {
    const int tid = threadIdx.x, bid = blockIdx.x;
    const int lrow = tid >> 7, j0 = (tid & 127) * 4;
    const int b = bid * 2 + lrow;
    const size_t rb = (size_t)b * H3;
    ushort4v ir4 = *(const ushort4v*)&gi[rb + j0];
    ushort4v iz4 = *(const ushort4v*)&gi[rb + 512 + j0];
    ushort4v in4 = *(const ushort4v*)&gi[rb + 1024 + j0];
    ushort4v hr4 = *(const ushort4v*)&gh[rb + j0];
    ushort4v hz4 = *(const ushort4v*)&gh[rb + 512 + j0];
    ushort4v hn4 = *(const ushort4v*)&gh[rb + 1024 + j0];
    float4 bir = *(const float4*)&b_ihl[j0];
    float4 biz = *(const float4*)&b_ihl[512 + j0];
    float4 bin = *(const float4*)&b_ihl[1024 + j0];
    float4 bhr = *(const float4*)&b_hhl[j0];
    float4 bhz = *(const float4*)&b_hhl[512 + j0];
    float4 bhn = *(const float4*)&b_hhl[1024 + j0];
    float4 h4 = *(const float4*)&h[rb + colOff + j0];
    float bi_r[4] = {bir.x, bir.y, bir.z, bir.w};
    float bi_z[4] = {biz.x, biz.y, biz.z, biz.w};
    float bi_n[4] = {bin.x, bin.y, bin.z, bin.w};
    float bh_r[4] = {bhr.x, bhr.y, bhr.z, bhr.w};
    float bh_z[4] = {bhz.x, bhz.y, bhz.z, bhz.w};
    float bh_n[4] = {bhn.x, bhn.y, bhn.z, bhn.w};
    float hv[4] = {h4.x, h4.y, h4.z, h4.w};
    float4 ho;
    ushort4v hbo;
#pragma unroll
    for (int k = 0; k < 4; ++k) {
        float r = sigmoidf_(bf2f(ir4[k]) + bi_r[k] + bf2f(hr4[k]) + bh_r[k]);
        float zg = sigmoidf_(bf2f(iz4[k]) + bi_z[k] + bf2f(hz4[k]) + bh_z[k]);
        float n = tanhf(bf2f(in4[k]) + bi_n[k] + r * (bf2f(hn4[k]) + bh_n[k]));
        float nh = (1.f - zg) * n + zg * hv[k];
        ((float*)&ho)[k] = nh;
        hbo[k] = f2bf(nh);
    }
    *(float4*)&h[rb + colOff + j0] = ho;
    *(ushort4v*)&h_bf[rb + colOff + j0] = hbo;
}

__global__ __launch_bounds__(256) void k_posfin(const float* partials, float* pos,
                                                const float* b2, float* out) {
    int b = blockIdx.x * 256 + threadIdx.x;
    float s0 = 0.f, s1 = 0.f;
#pragma unroll
    for (int s = 0; s < NSTRIP; ++s) {
        float2 v = *(const float2*)&partials[((size_t)s * BATCH + b) * 2];
        s0 += v.x; s1 += v.y;
    }
    float p0 = pos[b * 2 + 0] + s0 + b2[63 * 2 + 0];
    float p1 = pos[b * 2 + 1] + s1 + b2[63 * 2 + 1];
    out[((size_t)b * T_STEPS + 63) * 2 + 0] = p0;
    out[((size_t)b * T_STEPS + 63) * 2 + 1] = p1;
}

// ---- prologue helpers ----
__global__ __launch_bounds__(256) void k_comb(const float* z, const float* cond,
                                              unsigned short* comb, float* pos) {
    int idx = blockIdx.x * 256 + threadIdx.x;
    int b = idx >> 8, k = idx & 255;
    float v = (k < 128) ? z[b * 128 + k] : cond[b * 128 + (k - 128)];
    comb[idx] = f2bf(v);
    if (idx < BATCH * 2) pos[idx] = 0.f;
}

__global__ __launch_bounds__(256) void k_conv(const float* in, unsigned short* out) {
    size_t i = ((size_t)blockIdx.x * 256 + threadIdx.x) * 8;
    float4 v0 = *(const float4*)(in + i);
    float4 v1 = *(const float4*)(in + i + 4);
    ushort8v p;
    p[0] = f2bf(v0.x); p[1] = f2bf(v0.y); p[2] = f2bf(v0.z); p[3] = f2bf(v0.w);
    p[4] = f2bf(v1.x); p[5] = f2bf(v1.y); p[6] = f2bf(v1.z); p[7] = f2bf(v1.w);
    *(ushort8v*)(out + i) = p;
}

__global__ __launch_bounds__(256) void k_trw1(const float* W1, unsigned short* W1T) {
    __shared__ float tile[32][33];
    int t = blockIdx.z;
    int n0 = blockIdx.x * 32, k0 = blockIdx.y * 32;
    int tx = threadIdx.x & 31, ty = threadIdx.x >> 5;
#pragma unroll
    for (int j = 0; j < 4; ++j)
        tile[ty + 8 * j][tx] = W1[((size_t)t * 512 + k0 + ty + 8 * j) * 512 + n0 + tx];
    __syncthreads();
#pragma unroll
    for (int j = 0; j < 4; ++j)
        W1T[((size_t)t * 512 + n0 + ty + 8 * j) * 512 + k0 + tx] =
            f2bf(tile[tx][ty + 8 * j]);
}

extern "C" void kernel_launch(void* const* d_in, const int* in_sizes, int n_in,
                              void* d_out, int out_size, void* d_ws, size_t ws_size,
                              hipStream_t stream) {
    const float* z = (const float*)d_in[0];
    const float* cond = (const float*)d_in[1];
    const float* hp_W = (const float*)d_in[2];
    const float* hp_b = (const float*)d_in[3];
    const float* W_ih0 = (const float*)d_in[4];
    const float* W_ihr = (const float*)d_in[5];
    const float* W_hh = (const float*)d_in[6];
    const float* b_ih = (const float*)d_in[7];
    const float* b_hh = (const float*)d_in[8];
    const float* W1 = (const float*)d_in[9];
    const float* b1 = (const float*)d_in[10];
    const float* W2 = (const float*)d_in[11];
    const float* b2 = (const float*)d_in[12];
    float* out = (float*)d_out;

    char* w = (char*)d_ws;
    float* pos = (float*)w;           w += (size_t)BATCH * 2 * 4;
    float* partials = (float*)w;      w += (size_t)NSTRIP * BATCH * 2 * 4;
    float* h = (float*)w;             w += (size_t)BATCH * H3 * 4;
    unsigned short* gi = (unsigned short*)w;      w += (size_t)BATCH * H3 * 2;
    unsigned short* gh0 = (unsigned short*)w;     w += (size_t)BATCH * H3 * 2;
    unsigned short* gh1 = (unsigned short*)w;     w += (size_t)BATCH * H3 * 2;
    unsigned short* gh2 = (unsigned short*)w;     w += (size_t)BATCH * H3 * 2;
    unsigned short* h_bf = (unsigned short*)w;    w += (size_t)BATCH * H3 * 2;
    unsigned short* comb_bf = (unsigned short*)w; w += (size_t)BATCH * D_IN * 2;
    unsigned short* hpW_bf = (unsigned short*)w;  w += (size_t)H3 * D_IN * 2;
    unsigned short* Whh_bf = (unsigned short*)w;  w += (size_t)3 * H3 * H * 2;
    unsigned short* Wihr_bf = (unsigned short*)w; w += (size_t)2 * H3 * H * 2;
    unsigned short* W1T_bf = (unsigned short*)w;  w += (size_t)T_STEPS * H * H * 2;

    k_comb<<<dim3((BATCH * D_IN) / 256), dim3(256), 0, stream>>>(z, cond, comb_bf, pos);
    k_conv<<<dim3((H3 * D_IN) / 2048), dim3(256), 0, stream>>>(hp_W, hpW_bf);
    k_conv<<<dim3((3 * H3 * H) / 2048), dim3(256), 0, stream>>>(W_hh, Whh_bf);
    k_conv<<<dim3((2 * H3 * H) / 2048), dim3(256), 0, stream>>>(W_ihr, Wihr_bf);
    k_trw1<<<dim3(16, 16, T_STEPS), dim3(256), 0, stream>>>(W1, W1T_bf);
    k_init<<<dim3(192), dim3(256), 0, stream>>>(comb_bf, hpW_bf, h, h_bf, hp_b);
    k_gh3<<<dim3(576), dim3(256), 0, stream>>>(h_bf, Whh_bf, gh0, gh1, gh2);

    const unsigned short* Whh0 = Whh_bf;
    const unsigned short* Whh1 = Whh_bf + (size_t)H3 * H;
    const unsigned short* Whh2 = Whh_bf + (size_t)2 * H3 * H;
    const unsigned short* Wihr0 = Wihr_bf;
    const unsigned short* Wihr1 = Wihr_bf + (size_t)H3 * H;

    for (int t = 0; t < T_STEPS; ++t) {
        int last = (t == T_STEPS - 1) ? 1 : 0;
        k_ew0<<<dim3(1024), dim3(256), 0, stream>>>(gh0, h, h_bf, W_ih0, b_ih, b_hh,
                                                    pos, partials, b2, out, t);
        {   // B1: gi1(192) + gh0'[0:64)
            TD s0{h_bf, Wihr0, gi, 0};
            TD s1{h_bf, Whh0, gh0, 0};
            TD s2{nullptr, nullptr, nullptr, 0};
            k_tri<<<dim3(256), dim3(256), 0, stream>>>(s0, s1, s2, 192, 64, 0,
                                                       nullptr, nullptr, nullptr,
                                                       last);
        }
        k_ewl<<<dim3(1024), dim3(256), 0, stream>>>(gi, gh1, h, h_bf, b_ih + H3,
                                                    b_hh + H3, H);
        {   // B2: gi2(192) + gh1'[0:128) + gh0'[64:192)
            TD s0{h_bf + H, Wihr1, gi, 0};
            TD s1{h_bf + H, Whh1, gh1, 0};
            TD s2{h_bf, Whh0, gh0, 64};
            k_tri<<<dim3(448), dim3(256), 0, stream>>>(s0, s1, s2, 192, 128, 0,
                                                       nullptr, nullptr, nullptr,
                                                       last);
        }
        k_ewl<<<dim3(1024), dim3(256), 0, stream>>>(gi, gh2, h, h_bf, b_ih + 2 * H3,
                                                    b_hh + 2 * H3, 2 * H);
        {   // B3: MLP(64) + gh2'(192) + gh1'[128:192)
            TD s0{h_bf + 2 * H, W1T_bf + (size_t)t * H * H, nullptr, 0};
            TD s1{h_bf + 2 * H, Whh2, gh2, 0};
            TD s2{h_bf + H, Whh1, gh1, 128};
            k_tri<<<dim3(320), dim3(256), 0, stream>>>(
                s0, s1, s2, 64, 192, 1, b1 + (size_t)t * H,
                W2 + (size_t)t * H * 2, partials, last);
        }
    }
    k_posfin<<<dim3(8), dim3(256), 0, stream>>>(partials, pos, b2, out);
}

// Round 11
// 3849.371 us; speedup vs baseline: 1.1009x; 1.1009x over previous
//
#include <hip/hip_runtime.h>
#include <hip/hip_bf16.h>

// TrajectoryDecoder. L=3 GRU (H=512), T=64, B=2048. Round 11:
// R9 structure (best 4.19ms: 128x128 tiles, bf16 gates, 2-phase dbuf
// global_load_lds staging) + ONE change: BK 32 -> 64.
//   Halves per-block sync count (16 -> 8); same K-accumulation order
//   (kk=0 then kk=1 per 64-block) => bit-identical (absmax must stay 0.0625).
//   LDS 64KB/block -> 2 blocks/CU. Swizzle: 8 chunks/row, c ^= row&7.
// Per step (6 launches): k_ew0 | k_dual{gi1,gh0'} | k_ewl | k_dual{gi2,gh1'}
//                        | k_ewl | k_mlp_gh{MLP1+MLP2partials, gh2'}

#define H 512
#define T_STEPS 64
#define BATCH 2048
#define H3 1536
#define D_IN 256
#define NSTRIP 8

typedef __bf16 bf16x8 __attribute__((ext_vector_type(8)));
typedef float f32x4 __attribute__((ext_vector_type(4)));
typedef unsigned short ushort8v __attribute__((ext_vector_type(8)));
typedef unsigned short ushort4v __attribute__((ext_vector_type(4)));

typedef const __attribute__((address_space(1))) unsigned int* gp1_t;
typedef __attribute__((address_space(3))) unsigned int* lp3_t;

__device__ inline void gload16(const unsigned short* g, unsigned short* l) {
    __builtin_amdgcn_global_load_lds((gp1_t)g, (lp3_t)l, 16, 0, 0);
}

__device__ inline unsigned short f2bf(float f) {
    union { float f; unsigned int u; } v{f};
    unsigned int r = v.u + 0x7fffu + ((v.u >> 16) & 1u);
    return (unsigned short)(r >> 16);
}
__device__ inline float bf2f(unsigned short u) {
    union { unsigned int u; float f; } v;
    v.u = ((unsigned int)u) << 16;
    return v.f;
}
__device__ inline float sigmoidf_(float x) { return 1.f / (1.f + expf(-x)); }

// LDS short-offset: row r (64 shorts/row), data chunk kc (8 chunks/row).
// LDS slot s holds global chunk s ^ (r&7); read chunk kc at slot kc ^ (r&7).
__device__ inline int soff64(int r, int kc) {
    return r * 64 + ((kc ^ (r & 7)) << 3);
}

// stage 128 rows x 64 shorts (row stride ld) into linear LDS buf, swizzled src
__device__ inline void stage64(const unsigned short* src, int ld, int k0,
                               unsigned short* lds) {
    const int wid = threadIdx.x >> 6, lane = threadIdx.x & 63;
#pragma unroll
    for (int i = 0; i < 4; ++i) {
        int off = i * 4096 + wid * 1024 + lane * 16;  // byte offset in 16KB tile
        int row = off >> 7;            // 128B rows
        int c = (off >> 4) & 7;        // chunk within row
        int cs = c ^ (row & 7);        // swizzled source chunk (involution)
        gload16(src + (size_t)row * ld + k0 + cs * 8,
                lds + ((i * 4096 + wid * 1024) >> 1));
    }
}

// ---- 128x128 core, BK=64, 2-phase double-buffered: acc = A @ W^T ----
__device__ inline void gcore(const unsigned short* A0, int lda,
                             const unsigned short* W0, int K,
                             unsigned short (*As)[8192], unsigned short (*Ws)[8192],
                             f32x4 (&acc)[4][4]) {
    const int lane = threadIdx.x & 63, wid = threadIdx.x >> 6;
    const int wr = wid >> 1, wc = wid & 1;
    const int r16 = lane & 15, ko = lane >> 4;
#pragma unroll
    for (int i = 0; i < 4; ++i)
#pragma unroll
        for (int j = 0; j < 4; ++j) acc[i][j] = (f32x4)0.f;
    int aoff[2][4], boff[2][4];
#pragma unroll
    for (int kk = 0; kk < 2; ++kk)
#pragma unroll
        for (int i = 0; i < 4; ++i) {
            aoff[kk][i] = soff64(wr * 64 + i * 16 + r16, kk * 4 + ko);
            boff[kk][i] = soff64(wc * 64 + i * 16 + r16, kk * 4 + ko);
        }
    stage64(A0, lda, 0, As[0]);
    stage64(W0, K, 0, Ws[0]);
    __syncthreads();  // drains vmcnt(0)
    int cur = 0;
    for (int k0 = 0; k0 < K; k0 += 64) {
        const bool more = (k0 + 64) < K;
        if (more) {  // prefetch next 64-K tile into other buffer (overlaps MFMA)
            stage64(A0, lda, k0 + 64, As[cur ^ 1]);
            stage64(W0, K, k0 + 64, Ws[cur ^ 1]);
        }
#pragma unroll
        for (int kk = 0; kk < 2; ++kk) {  // same K order as BK=32 -> bit-identical
            bf16x8 a[4], b[4];
#pragma unroll
            for (int i = 0; i < 4; ++i) a[i] = *(const bf16x8*)&As[cur][aoff[kk][i]];
#pragma unroll
            for (int i = 0; i < 4; ++i) b[i] = *(const bf16x8*)&Ws[cur][boff[kk][i]];
#pragma unroll
            for (int mi = 0; mi < 4; ++mi)
#pragma unroll
                for (int ni = 0; ni < 4; ++ni)
                    acc[mi][ni] = __builtin_amdgcn_mfma_f32_16x16x32_bf16(
                        a[mi], b[ni], acc[mi][ni], 0, 0, 0);
        }
        if (more) {
            __syncthreads();  // next buffer written (vmcnt drain) + reads done
            cur ^= 1;
        }
    }
}

// fp32 (+ optional bf16 shadow) epilogue — used for h init
__device__ inline void epilogue_f32(f32x4 (&acc)[4][4], float* C, int ldc,
                                    const float* bias, unsigned short* Cbf,
                                    int brow, int bcol) {
    const int lane = threadIdx.x & 63, wid = threadIdx.x >> 6;
    const int wr = wid >> 1, wc = wid & 1, r16 = lane & 15;
    const int crow0 = brow + wr * 64 + (lane >> 4) * 4;
    const int ccol0 = bcol + wc * 64 + r16;
#pragma unroll
    for (int mi = 0; mi < 4; ++mi)
#pragma unroll
        for (int ni = 0; ni < 4; ++ni) {
            int col = ccol0 + ni * 16;
            float bv = bias ? bias[col] : 0.f;
#pragma unroll
            for (int j = 0; j < 4; ++j) {
                int row = crow0 + mi * 16 + j;
                float v = acc[mi][ni][j] + bv;
                C[(size_t)row * ldc + col] = v;
                if (Cbf) Cbf[(size_t)row * ldc + col] = f2bf(v);
            }
        }
}

// bf16 epilogue — used for gate buffers (gi, gh)
__device__ inline void epilogue_bf(f32x4 (&acc)[4][4], unsigned short* C, int ldc,
                                   int brow, int bcol) {
    const int lane = threadIdx.x & 63, wid = threadIdx.x >> 6;
    const int wr = wid >> 1, wc = wid & 1, r16 = lane & 15;
    const int crow0 = brow + wr * 64 + (lane >> 4) * 4;
    const int ccol0 = bcol + wc * 64 + r16;
#pragma unroll
    for (int mi = 0; mi < 4; ++mi)
#pragma unroll
        for (int ni = 0; ni < 4; ++ni) {
            int col = ccol0 + ni * 16;
#pragma unroll
            for (int j = 0; j < 4; ++j) {
                int row = crow0 + mi * 16 + j;
                C[(size_t)row * ldc + col] = f2bf(acc[mi][ni][j]);
            }
        }
}

// MLP epilogue: hid = relu(acc+b1); partials[strip][row][2] = hid @ W2-slice
__device__ inline void epilogue_mlp(f32x4 (&acc)[4][4], const float* b1t,
                                    const float* W2t, float* partials, int brow,
                                    int bcol) {
    const int lane = threadIdx.x & 63, wid = threadIdx.x >> 6;
    const int wr = wid >> 1, wc = wid & 1, r16 = lane & 15;
    const int crow0 = brow + wr * 64 + (lane >> 4) * 4;
    const int ccol0 = bcol + wc * 64 + r16;
    const int strip = (bcol >> 7) * 2 + wc;
    float d0[4][4], d1[4][4];
#pragma unroll
    for (int mi = 0; mi < 4; ++mi)
#pragma unroll
        for (int j = 0; j < 4; ++j) { d0[mi][j] = 0.f; d1[mi][j] = 0.f; }
#pragma unroll
    for (int ni = 0; ni < 4; ++ni) {
        int col = ccol0 + ni * 16;
        float bv = b1t[col];
        float w20 = W2t[col * 2 + 0], w21 = W2t[col * 2 + 1];
#pragma unroll
        for (int mi = 0; mi < 4; ++mi)
#pragma unroll
            for (int j = 0; j < 4; ++j) {
                float hv = fmaxf(acc[mi][ni][j] + bv, 0.f);
                d0[mi][j] += hv * w20;
                d1[mi][j] += hv * w21;
            }
    }
#pragma unroll
    for (int m = 1; m < 16; m <<= 1)
#pragma unroll
        for (int mi = 0; mi < 4; ++mi)
#pragma unroll
            for (int j = 0; j < 4; ++j) {
                d0[mi][j] += __shfl_xor(d0[mi][j], m);
                d1[mi][j] += __shfl_xor(d1[mi][j], m);
            }
    if (r16 == 0) {
#pragma unroll
        for (int mi = 0; mi < 4; ++mi)
#pragma unroll
            for (int j = 0; j < 4; ++j) {
                int row = crow0 + mi * 16 + j;
                float2 v = make_float2(d0[mi][j], d1[mi][j]);
                *(float2*)&partials[((size_t)strip * BATCH + row) * 2] = v;
            }
    }
}

// ---- GEMM kernels ----
__global__ __launch_bounds__(256) void k_init(const unsigned short* comb,
                                              const unsigned short* hpW, float* h,
                                              unsigned short* h_bf,
                                              const float* hp_b) {
    __shared__ unsigned short As[2][8192], Ws[2][8192];
    f32x4 acc[4][4];
    int bid = blockIdx.x;  // 192
    int brow = (bid / 12) * 128, bcol = (bid % 12) * 128;
    gcore(comb + (size_t)brow * D_IN, D_IN, hpW + (size_t)bcol * D_IN, D_IN, As, Ws,
          acc);
    epilogue_f32(acc, h, H3, hp_b, h_bf, brow, bcol);
}

__global__ __launch_bounds__(256) void k_gh3(const unsigned short* h_bf,
                                             const unsigned short* Whh,
                                             unsigned short* gh0, unsigned short* gh1,
                                             unsigned short* gh2) {
    __shared__ unsigned short As[2][8192], Ws[2][8192];
    f32x4 acc[4][4];
    int bid = blockIdx.x;  // 576
    int g = bid / 192, r = bid % 192;
    int brow = (r / 12) * 128, bcol = (r % 12) * 128;
    unsigned short* C = (g == 0) ? gh0 : (g == 1 ? gh1 : gh2);
    gcore(h_bf + g * H + (size_t)brow * H3, H3,
          Whh + (size_t)g * H3 * H + (size_t)bcol * H, H, As, Ws, acc);
    epilogue_bf(acc, C, H3, brow, bcol);
}

__global__ __launch_bounds__(256) void k_dual(const unsigned short* A,
                                              const unsigned short* W0,
                                              unsigned short* C0,
                                              const unsigned short* W1,
                                              unsigned short* C1, int skip2) {
    __shared__ unsigned short As[2][8192], Ws[2][8192];
    f32x4 acc[4][4];
    int bid = blockIdx.x;  // 384
    int half = bid >= 192;
    if (half && skip2) return;
    int r = bid - half * 192;
    int brow = (r / 12) * 128, bcol = (r % 12) * 128;
    const unsigned short* W = half ? W1 : W0;
    unsigned short* C = half ? C1 : C0;
    gcore(A + (size_t)brow * H3, H3, W + (size_t)bcol * H, H, As, Ws, acc);
    epilogue_bf(acc, C, H3, brow, bcol);
}

__global__ __launch_bounds__(256) void k_mlp_gh(const unsigned short* A,
                                                const unsigned short* W1Tt,
                                                const float* b1t, const float* W2t,
                                                float* partials,
                                                const unsigned short* Whh2,
                                                unsigned short* gh2, int skip2) {
    __shared__ unsigned short As[2][8192], Ws[2][8192];
    f32x4 acc[4][4];
    int bid = blockIdx.x;  // 256 = 64 MLP + 192 gh2
    if (bid < 64) {
        int brow = (bid >> 2) * 128, bcol = (bid & 3) * 128;
        gcore(A + (size_t)brow * H3, H3, W1Tt + (size_t)bcol * H, H, As, Ws, acc);
        epilogue_mlp(acc, b1t, W2t, partials, brow, bcol);
    } else {
        if (skip2) return;
        int r = bid - 64;
        int brow = (r / 12) * 128, bcol = (r % 12) * 128;
        gcore(A + (size_t)brow * H3, H3, Whh2 + (size_t)bcol * H, H, As, Ws, acc);
        epilogue_bf(acc, gh2, H3, brow, bcol);
    }
}

// ---- EW kernels (1024 blocks, 2 rows/block, 4 elems/thread) ----
__global__ __launch_bounds__(256) void k_ew0(const unsigned short* gh0, float* h,
                                             unsigned short* h_bf,
                                             const float* W_ih0, const float* b_ih,
                                             const float* b_hh, float* pos,
                                             const float* partials, const float* b2,
                                             float* out, int t) {
    __shared__ float posS[2][2];
    const int tid = threadIdx.x, bid = blockIdx.x;
    if (tid < 2) {
        int b = bid * 2 + tid;
        float p0 = pos[b * 2 + 0], p1 = pos[b * 2 + 1];
        if (t > 0) {
            float s0 = 0.f, s1 = 0.f;
#pragma unroll
            for (int s = 0; s < NSTRIP; ++s) {
                float2 v = *(const float2*)&partials[((size_t)s * BATCH + b) * 2];
                s0 += v.x; s1 += v.y;
            }
            p0 += s0 + b2[(t - 1) * 2 + 0];
            p1 += s1 + b2[(t - 1) * 2 + 1];
            pos[b * 2 + 0] = p0;
            pos[b * 2 + 1] = p1;
            out[((size_t)b * T_STEPS + (t - 1)) * 2 + 0] = p0;
            out[((size_t)b * T_STEPS + (t - 1)) * 2 + 1] = p1;
        }
        posS[tid][0] = p0;
        posS[tid][1] = p1;
    }
    __syncthreads();
    const int lrow = tid >> 7, j0 = (tid & 127) * 4;
    const int b = bid * 2 + lrow;
    const size_t rb = (size_t)b * H3;
    const float px = posS[lrow][0], py = posS[lrow][1];
    ushort4v g0 = *(const ushort4v*)&gh0[rb + j0];
    ushort4v g1 = *(const ushort4v*)&gh0[rb + 512 + j0];
    ushort4v g2 = *(const ushort4v*)&gh0[rb + 1024 + j0];
    float4 h4 = *(const float4*)&h[rb + j0];
    float hv[4] = {h4.x, h4.y, h4.z, h4.w};
    float4 ho;
    ushort4v hbo;
#pragma unroll
    for (int k = 0; k < 4; ++k) {
        int j = j0 + k;
        float gi_r = px * W_ih0[j * 2 + 0] + py * W_ih0[j * 2 + 1] + b_ih[j];
        float gi_z = px * W_ih0[(512 + j) * 2 + 0] + py * W_ih0[(512 + j) * 2 + 1] +
                     b_ih[512 + j];
        float gi_n = px * W_ih0[(1024 + j) * 2 + 0] + py * W_ih0[(1024 + j) * 2 + 1] +
                     b_ih[1024 + j];
        float r = sigmoidf_(gi_r + bf2f(g0[k]) + b_hh[j]);
        float zg = sigmoidf_(gi_z + bf2f(g1[k]) + b_hh[512 + j]);
        float n = tanhf(gi_n + r * (bf2f(g2[k]) + b_hh[1024 + j]));
        float nh = (1.f - zg) * n + zg * hv[k];
        ((float*)&ho)[k] = nh;
        hbo[k] = f2bf(nh);
    }
    *(float4*)&h[rb + j0] = ho;
    *(ushort4v*)&h_bf[rb + j0] = hbo;
}

__global__ __launch_bounds__(256) void k_ewl(const unsigned short* gi,
                                             const unsigned short* gh, float* h,
                                             unsigned short* h_bf,
                                             const float* b_ihl, const float* b_hhl,
                                             int colOff) {
    const int tid = threadIdx.x, bid = blockIdx.x;
    const int lrow = tid >> 7, j0 = (tid & 127) * 4;
    const int b = bid * 2 + lrow;
    const size_t rb = (size_t)b * H3;
    ushort4v ir4 = *(const ushort4v*)&gi[rb + j0];
    ushort4v iz4 = *(const ushort4v*)&gi[rb + 512 + j0];
    ushort4v in4 = *(const ushort4v*)&gi[rb + 1024 + j0];
    ushort4v hr4 = *(const ushort4v*)&gh[rb + j0];
    ushort4v hz4 = *(const ushort4v*)&gh[rb + 512 + j0];
    ushort4v hn4 = *(const ushort4v*)&gh[rb + 1024 + j0];
    float4 bir = *(const float4*)&b_ihl[j0];
    float4 biz = *(const float4*)&b_ihl[512 + j0];
    float4 bin = *(const float4*)&b_ihl[1024 + j0];
    float4 bhr = *(const float4*)&b_hhl[j0];
    float4 bhz = *(const float4*)&b_hhl[512 + j0];
    float4 bhn = *(const float4*)&b_hhl[1024 + j0];
    float4 h4 = *(const float4*)&h[rb + colOff + j0];
    float bi_r[4] = {bir.x, bir.y, bir.z, bir.w};
    float bi_z[4] = {biz.x, biz.y, biz.z, biz.w};
    float bi_n[4] = {bin.x, bin.y, bin.z, bin.w};
    float bh_r[4] = {bhr.x, bhr.y, bhr.z, bhr.w};
    float bh_z[4] = {bhz.x, bhz.y, bhz.z, bhz.w};
    float bh_n[4] = {bhn.x, bhn.y, bhn.z, bhn.w};
    float hv[4] = {h4.x, h4.y, h4.z, h4.w};
    float4 ho;
    ushort4v hbo;
#pragma unroll
    for (int k = 0; k < 4; ++k) {
        float r = sigmoidf_(bf2f(ir4[k]) + bi_r[k] + bf2f(hr4[k]) + bh_r[k]);
        float zg = sigmoidf_(bf2f(iz4[k]) + bi_z[k] + bf2f(hz4[k]) + bh_z[k]);
        float n = tanhf(bf2f(in4[k]) + bi_n[k] + r * (bf2f(hn4[k]) + bh_n[k]));
        float nh = (1.f - zg) * n + zg * hv[k];
        ((float*)&ho)[k] = nh;
        hbo[k] = f2bf(nh);
    }
    *(float4*)&h[rb + colOff + j0] = ho;
    *(ushort4v*)&h_bf[rb + colOff + j0] = hbo;
}

__global__ __launch_bounds__(256) void k_posfin(const float* partials, float* pos,
                                                const float* b2, float* out) {
    int b = blockIdx.x * 256 + threadIdx.x;
    float s0 = 0.f, s1 = 0.f;
#pragma unroll
    for (int s = 0; s < NSTRIP; ++s) {
        float2 v = *(const float2*)&partials[((size_t)s * BATCH + b) * 2];
        s0 += v.x; s1 += v.y;
    }
    float p0 = pos[b * 2 + 0] + s0 + b2[63 * 2 + 0];
    float p1 = pos[b * 2 + 1] + s1 + b2[63 * 2 + 1];
    out[((size_t)b * T_STEPS + 63) * 2 + 0] = p0;
    out[((size_t)b * T_STEPS + 63) * 2 + 1] = p1;
}

// ---- prologue helpers ----
__global__ __launch_bounds__(256) void k_comb(const float* z, const float* cond,
                                              unsigned short* comb, float* pos) {
    int idx = blockIdx.x * 256 + threadIdx.x;
    int b = idx >> 8, k = idx & 255;
    float v = (k < 128) ? z[b * 128 + k] : cond[b * 128 + (k - 128)];
    comb[idx] = f2bf(v);
    if (idx < BATCH * 2) pos[idx] = 0.f;
}

__global__ __launch_bounds__(256) void k_conv(const float* in, unsigned short* out) {
    size_t i = ((size_t)blockIdx.x * 256 + threadIdx.x) * 8;
    float4 v0 = *(const float4*)(in + i);
    float4 v1 = *(const float4*)(in + i + 4);
    ushort8v p;
    p[0] = f2bf(v0.x); p[1] = f2bf(v0.y); p[2] = f2bf(v0.z); p[3] = f2bf(v0.w);
    p[4] = f2bf(v1.x); p[5] = f2bf(v1.y); p[6] = f2bf(v1.z); p[7] = f2bf(v1.w);
    *(ushort8v*)(out + i) = p;
}

__global__ __launch_bounds__(256) void k_trw1(const float* W1, unsigned short* W1T) {
    __shared__ float tile[32][33];
    int t = blockIdx.z;
    int n0 = blockIdx.x * 32, k0 = blockIdx.y * 32;
    int tx = threadIdx.x & 31, ty = threadIdx.x >> 5;
#pragma unroll
    for (int j = 0; j < 4; ++j)
        tile[ty + 8 * j][tx] = W1[((size_t)t * 512 + k0 + ty + 8 * j) * 512 + n0 + tx];
    __syncthreads();
#pragma unroll
    for (int j = 0; j < 4; ++j)
        W1T[((size_t)t * 512 + n0 + ty + 8 * j) * 512 + k0 + tx] =
            f2bf(tile[tx][ty + 8 * j]);
}

extern "C" void kernel_launch(void* const* d_in, const int* in_sizes, int n_in,
                              void* d_out, int out_size, void* d_ws, size_t ws_size,
                              hipStream_t stream) {
    const float* z = (const float*)d_in[0];
    const float* cond = (const float*)d_in[1];
    const float* hp_W = (const float*)d_in[2];
    const float* hp_b = (const float*)d_in[3];
    const float* W_ih0 = (const float*)d_in[4];
    const float* W_ihr = (const float*)d_in[5];
    const float* W_hh = (const float*)d_in[6];
    const float* b_ih = (const float*)d_in[7];
    const float* b_hh = (const float*)d_in[8];
    const float* W1 = (const float*)d_in[9];
    const float* b1 = (const float*)d_in[10];
    const float* W2 = (const float*)d_in[11];
    const float* b2 = (const float*)d_in[12];
    float* out = (float*)d_out;

    char* w = (char*)d_ws;
    float* pos = (float*)w;           w += (size_t)BATCH * 2 * 4;
    float* partials = (float*)w;      w += (size_t)NSTRIP * BATCH * 2 * 4;
    float* h = (float*)w;             w += (size_t)BATCH * H3 * 4;
    unsigned short* gi = (unsigned short*)w;      w += (size_t)BATCH * H3 * 2;
    unsigned short* gh0 = (unsigned short*)w;     w += (size_t)BATCH * H3 * 2;
    unsigned short* gh1 = (unsigned short*)w;     w += (size_t)BATCH * H3 * 2;
    unsigned short* gh2 = (unsigned short*)w;     w += (size_t)BATCH * H3 * 2;
    unsigned short* h_bf = (unsigned short*)w;    w += (size_t)BATCH * H3 * 2;
    unsigned short* comb_bf = (unsigned short*)w; w += (size_t)BATCH * D_IN * 2;
    unsigned short* hpW_bf = (unsigned short*)w;  w += (size_t)H3 * D_IN * 2;
    unsigned short* Whh_bf = (unsigned short*)w;  w += (size_t)3 * H3 * H * 2;
    unsigned short* Wihr_bf = (unsigned short*)w; w += (size_t)2 * H3 * H * 2;
    unsigned short* W1T_bf = (unsigned short*)w;  w += (size_t)T_STEPS * H * H * 2;

    k_comb<<<dim3((BATCH * D_IN) / 256), dim3(256), 0, stream>>>(z, cond, comb_bf, pos);
    k_conv<<<dim3((H3 * D_IN) / 2048), dim3(256), 0, stream>>>(hp_W, hpW_bf);
    k_conv<<<dim3((3 * H3 * H) / 2048), dim3(256), 0, stream>>>(W_hh, Whh_bf);
    k_conv<<<dim3((2 * H3 * H) / 2048), dim3(256), 0, stream>>>(W_ihr, Wihr_bf);
    k_trw1<<<dim3(16, 16, T_STEPS), dim3(256), 0, stream>>>(W1, W1T_bf);
    k_init<<<dim3(192), dim3(256), 0, stream>>>(comb_bf, hpW_bf, h, h_bf, hp_b);
    k_gh3<<<dim3(576), dim3(256), 0, stream>>>(h_bf, Whh_bf, gh0, gh1, gh2);

    for (int t = 0; t < T_STEPS; ++t) {
        int last = (t == T_STEPS - 1) ? 1 : 0;
        k_ew0<<<dim3(1024), dim3(256), 0, stream>>>(gh0, h, h_bf, W_ih0, b_ih, b_hh,
                                                    pos, partials, b2, out, t);
        k_dual<<<dim3(384), dim3(256), 0, stream>>>(h_bf, Wihr_bf, gi, Whh_bf, gh0,
                                                    last);
        k_ewl<<<dim3(1024), dim3(256), 0, stream>>>(gi, gh1, h, h_bf, b_ih + H3,
                                                    b_hh + H3, H);
        k_dual<<<dim3(384), dim3(256), 0, stream>>>(
            h_bf + H, Wihr_bf + (size_t)H3 * H, gi, Whh_bf + (size_t)H3 * H, gh1,
            last);
        k_ewl<<<dim3(1024), dim3(256), 0, stream>>>(gi, gh2, h, h_bf, b_ih + 2 * H3,
                                                    b_hh + 2 * H3, 2 * H);
        k_mlp_gh<<<dim3(256), dim3(256), 0, stream>>>(
            h_bf + 2 * H, W1T_bf + (size_t)t * H * H, b1 + (size_t)t * H,
            W2 + (size_t)t * H * 2, partials, Whh_bf + (size_t)2 * H3 * H, gh2, last);
    }
    k_posfin<<<dim3(8), dim3(256), 0, stream>>>(partials, pos, b2, out);
}